// Round 6
// baseline (20.652 us; speedup 1.0000x reference)
//
#include <hip/hip_runtime.h>
#include <stdint.h>

typedef __attribute__((ext_vector_type(8))) short short8;
typedef __attribute__((ext_vector_type(4))) float f32x4;

namespace {
constexpr int   kN     = 50;
constexpr int   kD     = 128;
constexpr float kNeg   = -9.0e15f;
constexpr float kSlope = 0.2f;
constexpr int   HS32   = 132;   // Hf stride (f32): PV reads 2-way max
constexpr int   HS16   = 136;   // Hhi/Hlo stride (shorts): 16B-aligned rows
constexpr int   SS     = 68;    // Sa stride (f32), 32 rows per block
constexpr int   AS     = 36;    // At stride (shorts): [j][i] bf16, b64-aligned reads
}

union Pack8 { uint32_t u[4]; short8 s; };

__global__ __launch_bounds__(512)
void gat_v6_kernel(const float* __restrict__ hidden,
                   const int*   __restrict__ adj,
                   const float* __restrict__ a0,
                   const float* __restrict__ a1,
                   const float* __restrict__ a2,
                   const float* __restrict__ a3,
                   float* __restrict__ out)
{
    __shared__ float          Hf [kN * HS32];   // 26.4 KB f32 H (PV B-side)
    __shared__ unsigned short Hhi[64 * HS16];   // 17.4 KB bf16 hi(H), rows>=50 zero
    __shared__ unsigned short Hlo[64 * HS16];   // 17.4 KB bf16 lo(H)
    __shared__ float          Sa [32 * SS];     //  8.7 KB raw selected scores (block's i-rows)
    __shared__ unsigned short At [64 * AS];     //  4.6 KB attn bf16-RN, [j][i-local]
    // total 74.5 KB -> 2 blocks/CU

    const int b    = blockIdx.x >> 1;
    const int ih   = blockIdx.x & 1;            // i-half: rows 0..31 / 32..49
    const int tid  = threadIdx.x;
    const int lane = tid & 63;
    const int wid  = __builtin_amdgcn_readfirstlane(tid >> 6);
    const int g    = lane >> 4;
    const int f    = lane & 15;

    const float* __restrict__ hb   = hidden + (size_t)b * (kN * kD);
    const int*   __restrict__ adjb = adj    + (size_t)b * (kN * kN);
    float*       __restrict__ outb = out    + (size_t)b * (kN * kD);

    // ---------------- phase 1: stage H (f32 + hi/lo bf16 split), zero pad rows ----------------
    const float4* hg = reinterpret_cast<const float4*>(hb);
    #pragma unroll
    for (int it4 = 0; it4 < 4; ++it4) {
        const int idx = tid + it4 * 512;        // 0..2047 over 64 rows x 32 float4
        const int j   = idx >> 5;
        const int d4  = idx & 31;
        float4 v = make_float4(0.f, 0.f, 0.f, 0.f);
        if (j < kN) v = hg[j * 32 + d4];

        const uint32_t h0 = __float_as_uint(v.x) & 0xffff0000u;
        const uint32_t h1 = __float_as_uint(v.y) & 0xffff0000u;
        const uint32_t h2 = __float_as_uint(v.z) & 0xffff0000u;
        const uint32_t h3 = __float_as_uint(v.w) & 0xffff0000u;
        uint2 hiw;
        hiw.x = h1 | (h0 >> 16);
        hiw.y = h3 | (h2 >> 16);
        const float r0 = v.x - __uint_as_float(h0);
        const float r1 = v.y - __uint_as_float(h1);
        const float r2 = v.z - __uint_as_float(h2);
        const float r3 = v.w - __uint_as_float(h3);
        uint2 low;
        low.x = (__float_as_uint(r1) & 0xffff0000u) | (__float_as_uint(r0) >> 16);
        low.y = (__float_as_uint(r3) & 0xffff0000u) | (__float_as_uint(r2) >> 16);
        *reinterpret_cast<uint2*>(&Hhi[j * HS16 + 4 * d4]) = hiw;
        *reinterpret_cast<uint2*>(&Hlo[j * HS16 + 4 * d4]) = low;
        if (j < kN) *reinterpret_cast<float4*>(&Hf[j * HS32 + 4 * d4]) = v;
    }
    __syncthreads();

    // ---------------- phase 2: scores via MFMA (hi/lo 3-term), wave = (itL, jt) ----------------
    {
        const int jt   = wid & 3;
        const int itL  = wid >> 2;              // 0..1
        const int itG  = 2 * ih + itL;
        const int i0   = 16 * itG;
        const int irow = (i0 + f < kN) ? (i0 + f) : (kN - 1);
        const int jrow = 16 * jt + f;           // 0..63 (rows>=50 are zeros)

        f32x4 acc[4];
        #pragma unroll
        for (int k = 0; k < 4; ++k) acc[k] = (f32x4){0.f, 0.f, 0.f, 0.f};

        const float* __restrict__ aks[4] = {a0, a1, a2, a3};

        #pragma unroll
        for (int ksl = 0; ksl < 4; ++ksl) {
            const int dofs = 32 * ksl + 8 * g;

            // A-side: reconstruct h_i (f32) from hi/lo bf16
            const short8 ah8 = *reinterpret_cast<const short8*>(&Hhi[irow * HS16 + dofs]);
            const short8 al8 = *reinterpret_cast<const short8*>(&Hlo[irow * HS16 + dofs]);
            float ha[8];
            #pragma unroll
            for (int p = 0; p < 8; ++p) {
                const uint32_t uh = ((uint32_t)(unsigned short)ah8[p]) << 16;
                const uint32_t ul = ((uint32_t)(unsigned short)al8[p]) << 16;
                ha[p] = __uint_as_float(uh) + __uint_as_float(ul);
            }

            // B-side fragments (shared across k)
            const short8 bh = *reinterpret_cast<const short8*>(&Hhi[jrow * HS16 + dofs]);
            const short8 bl = *reinterpret_cast<const short8*>(&Hlo[jrow * HS16 + dofs]);

            #pragma unroll
            for (int k = 0; k < 4; ++k) {
                // a_k slice from global (L1-resident, per-lane)
                const float4 av0 = *reinterpret_cast<const float4*>(aks[k] + dofs);
                const float4 av1 = *reinterpret_cast<const float4*>(aks[k] + dofs + 4);
                const float aa[8] = {av0.x, av0.y, av0.z, av0.w, av1.x, av1.y, av1.z, av1.w};
                Pack8 ph, pl;
                #pragma unroll
                for (int p = 0; p < 4; ++p) {
                    const float q0 = ha[2 * p]     * aa[2 * p];
                    const float q1 = ha[2 * p + 1] * aa[2 * p + 1];
                    const uint32_t b0 = __float_as_uint(q0) & 0xffff0000u;
                    const uint32_t b1 = __float_as_uint(q1) & 0xffff0000u;
                    ph.u[p] = b1 | (b0 >> 16);
                    const float s0 = q0 - __uint_as_float(b0);
                    const float s1 = q1 - __uint_as_float(b1);
                    pl.u[p] = (__float_as_uint(s1) & 0xffff0000u) | (__float_as_uint(s0) >> 16);
                }
                acc[k] = __builtin_amdgcn_mfma_f32_16x16x32_bf16(ph.s, bh, acc[k], 0, 0, 0);
                acc[k] = __builtin_amdgcn_mfma_f32_16x16x32_bf16(ph.s, bl, acc[k], 0, 0, 0);
                acc[k] = __builtin_amdgcn_mfma_f32_16x16x32_bf16(pl.s, bh, acc[k], 0, 0, 0);
            }
        }

        // select by edge type, write raw scores for this block's local i rows
        const int j = 16 * jt + f;
        #pragma unroll
        for (int reg = 0; reg < 4; ++reg) {
            const int iL = 16 * itL + 4 * g + reg;   // 0..31 local
            const int ii = 32 * ih + iL;             // global row
            if (ii < kN && j < kN) {
                const int adjv = adjb[ii * kN + j];
                const float val = (adjv == 1) ? acc[0][reg]
                                : (adjv == 2) ? acc[1][reg]
                                : (adjv == 3) ? acc[2][reg]
                                : (adjv == 4) ? acc[3][reg] : 0.f;
                Sa[iL * SS + j] = val;
            }
        }
    }
    __syncthreads();

    // ---------------- phase 3: softmax (wave per row), write attn bf16-RN transposed ----------------
    {
        const int icount = ih ? (kN - 32) : 32;      // 18 or 32
        float attv[4];
        #pragma unroll
        for (int t = 0; t < 4; ++t) {
            const int rL = wid + 8 * t;              // 0..31
            const int r  = 32 * ih + rL;
            const bool rowv = (rL < icount);
            const float x = Sa[rL * SS + lane];      // in-bounds always; garbage if !rowv
            int adjv = 0;
            if (rowv && lane < kN) adjv = adjb[r * kN + lane];
            const bool valid = (adjv >= 1) && (adjv <= 4);
            const float lx = (x > 0.f) ? x : kSlope * x;
            float s = valid ? lx : kNeg;
            float m = s;
            #pragma unroll
            for (int o = 32; o; o >>= 1) m = fmaxf(m, __shfl_xor(m, o));
            const float e = (lane < kN) ? __expf(s - m) : 0.f;  // all-masked row -> uniform (matches ref)
            float ts = e;
            #pragma unroll
            for (int o = 32; o; o >>= 1) ts += __shfl_xor(ts, o);
            attv[t] = e / ts;
        }
        #pragma unroll
        for (int t = 0; t < 4; ++t) {
            const int rL = wid + 8 * t;
            if (rL < icount) {
                uint32_t u = __float_as_uint(attv[t]);
                u += 0x7fffu + ((u >> 16) & 1u);     // round-to-nearest bf16
                At[lane * AS + rL] = (unsigned short)(u >> 16);
            }
        }
    }
    __syncthreads();

    // ---------------- phase 4: PV fp32: out[i,:] = sum_j attn[i,j] h[j,:] ----------------
    if (wid < 4) {
        const int itL = wid & 1;
        const int dh  = wid >> 1;
        const int i0L = 16 * itL;
        const int db  = 64 * dh + 4 * f;

        f32x4 o0 = {0.f, 0.f, 0.f, 0.f}, o1 = o0, o2 = o0, o3 = o0;
        #pragma unroll 5
        for (int j = 0; j < kN; ++j) {
            const float4  hv = *reinterpret_cast<const float4*>(&Hf[j * HS32 + db]);
            const ushort4 a4 = *reinterpret_cast<const ushort4*>(&At[j * AS + i0L + 4 * g]);
            const float av0 = __uint_as_float(((uint32_t)a4.x) << 16);
            const float av1 = __uint_as_float(((uint32_t)a4.y) << 16);
            const float av2 = __uint_as_float(((uint32_t)a4.z) << 16);
            const float av3 = __uint_as_float(((uint32_t)a4.w) << 16);
            o0.x += av0 * hv.x; o0.y += av0 * hv.y; o0.z += av0 * hv.z; o0.w += av0 * hv.w;
            o1.x += av1 * hv.x; o1.y += av1 * hv.y; o1.z += av1 * hv.z; o1.w += av1 * hv.w;
            o2.x += av2 * hv.x; o2.y += av2 * hv.y; o2.z += av2 * hv.z; o2.w += av2 * hv.w;
            o3.x += av3 * hv.x; o3.y += av3 * hv.y; o3.z += av3 * hv.z; o3.w += av3 * hv.w;
        }
        const int iiB = 32 * ih + i0L + 4 * g;
        if (iiB + 0 < kN) *reinterpret_cast<f32x4*>(&outb[(iiB + 0) * kD + db]) = o0;
        if (iiB + 1 < kN) *reinterpret_cast<f32x4*>(&outb[(iiB + 1) * kD + db]) = o1;
        if (iiB + 2 < kN) *reinterpret_cast<f32x4*>(&outb[(iiB + 2) * kD + db]) = o2;
        if (iiB + 3 < kN) *reinterpret_cast<f32x4*>(&outb[(iiB + 3) * kD + db]) = o3;
    }
}

extern "C" void kernel_launch(void* const* d_in, const int* in_sizes, int n_in,
                              void* d_out, int out_size, void* d_ws, size_t ws_size,
                              hipStream_t stream) {
    const float* hidden = reinterpret_cast<const float*>(d_in[0]);
    const int*   adjp   = reinterpret_cast<const int*>(d_in[1]);
    const float* a0     = reinterpret_cast<const float*>(d_in[2]);
    const float* a1     = reinterpret_cast<const float*>(d_in[3]);
    const float* a2     = reinterpret_cast<const float*>(d_in[4]);
    const float* a3     = reinterpret_cast<const float*>(d_in[5]);
    float*       outp   = reinterpret_cast<float*>(d_out);

    gat_v6_kernel<<<dim3(512), dim3(512), 0, stream>>>(
        hidden, adjp, a0, a1, a2, a3, outp);
}

// Round 7
// 20.086 us; speedup vs baseline: 1.0282x; 1.0282x over previous
//
#include <hip/hip_runtime.h>
#include <stdint.h>

typedef __attribute__((ext_vector_type(8))) short short8;
typedef __attribute__((ext_vector_type(4))) float f32x4;

namespace {
constexpr int   kN     = 50;
constexpr int   kD     = 128;
constexpr float kNeg   = -9.0e15f;
constexpr float kSlope = 0.2f;
constexpr int   HS32   = 132;   // Hf stride (f32)
constexpr int   HS16   = 136;   // Hhi/Hlo stride (shorts), 16B-aligned rows
constexpr int   SS     = 68;    // Sa stride (f32)
constexpr int   AS     = 36;    // At stride (shorts): 72B rows, 8B-aligned reads
constexpr int   ADS    = 52;    // adj byte-stride
}

union Pack8 { uint32_t u[4]; short8 s; };

__global__ __launch_bounds__(512)
void gat_v7_kernel(const float* __restrict__ hidden,
                   const int*   __restrict__ adj,
                   const float* __restrict__ a0,
                   const float* __restrict__ a1,
                   const float* __restrict__ a2,
                   const float* __restrict__ a3,
                   float* __restrict__ out)
{
    __shared__ float          Hf [kN * HS32];   // 26.4 KB f32 H (ph2 A-side + PV B-side)
    __shared__ unsigned short Hhi[64 * HS16];   // 17.4 KB bf16 hi(H), rows>=50 zero
    __shared__ unsigned short Hlo[64 * HS16];   // 17.4 KB bf16 lo(H)
    __shared__ float          Sa [32 * SS];     //  8.7 KB final logits (select+leaky+mask done)
    __shared__ unsigned short At [64 * AS];     //  4.6 KB attn bf16-RN, [j][i-local]
    __shared__ unsigned char  Ad [kN * ADS];    //  2.6 KB adj bytes
    // total 77.1 KB -> 2 blocks/CU

    const int b    = blockIdx.x >> 1;
    const int ih   = blockIdx.x & 1;            // i-half: rows 0..31 / 32..49
    const int tid  = threadIdx.x;
    const int lane = tid & 63;
    const int wid  = __builtin_amdgcn_readfirstlane(tid >> 6);
    const int g    = lane >> 4;
    const int f    = lane & 15;

    const float* __restrict__ hb   = hidden + (size_t)b * (kN * kD);
    const int*   __restrict__ adjb = adj    + (size_t)b * (kN * kN);
    float*       __restrict__ outb = out    + (size_t)b * (kN * kD);

    // ---------------- phase 1: stage H (f32 + hi/lo bf16) and adj bytes ----------------
    const float4* hg = reinterpret_cast<const float4*>(hb);
    #pragma unroll
    for (int it4 = 0; it4 < 4; ++it4) {
        const int idx = tid + it4 * 512;        // 0..2047 over 64 rows x 32 float4
        const int j   = idx >> 5;
        const int d4  = idx & 31;
        float4 v = make_float4(0.f, 0.f, 0.f, 0.f);
        if (j < kN) v = hg[j * 32 + d4];

        const uint32_t h0 = __float_as_uint(v.x) & 0xffff0000u;
        const uint32_t h1 = __float_as_uint(v.y) & 0xffff0000u;
        const uint32_t h2 = __float_as_uint(v.z) & 0xffff0000u;
        const uint32_t h3 = __float_as_uint(v.w) & 0xffff0000u;
        uint2 hiw;
        hiw.x = h1 | (h0 >> 16);
        hiw.y = h3 | (h2 >> 16);
        const float r0 = v.x - __uint_as_float(h0);
        const float r1 = v.y - __uint_as_float(h1);
        const float r2 = v.z - __uint_as_float(h2);
        const float r3 = v.w - __uint_as_float(h3);
        uint2 low;
        low.x = (__float_as_uint(r1) & 0xffff0000u) | (__float_as_uint(r0) >> 16);
        low.y = (__float_as_uint(r3) & 0xffff0000u) | (__float_as_uint(r2) >> 16);
        *reinterpret_cast<uint2*>(&Hhi[j * HS16 + 4 * d4]) = hiw;
        *reinterpret_cast<uint2*>(&Hlo[j * HS16 + 4 * d4]) = low;
        if (j < kN) *reinterpret_cast<float4*>(&Hf[j * HS32 + 4 * d4]) = v;
    }
    // adj -> LDS bytes (2500 ints = 625 int4, coalesced)
    for (int idx = tid; idx < 625; idx += 512) {
        const int4 v = reinterpret_cast<const int4*>(adjb)[idx];
        const int e = 4 * idx;
        const int vv[4] = {v.x, v.y, v.z, v.w};
        #pragma unroll
        for (int p = 0; p < 4; ++p) {
            const int ee  = e + p;
            const int row = ee / kN;
            const int col = ee - kN * row;
            Ad[row * ADS + col] = (unsigned char)vv[p];
        }
    }
    __syncthreads();

    // ---------------- phase 2: scores via MFMA (hi/lo 3-term), wave = (itL, jt) ----------------
    {
        const int jt   = wid & 3;
        const int itL  = wid >> 2;              // 0..1
        const int itG  = 2 * ih + itL;
        const int i0   = 16 * itG;
        const int irow = (i0 + f < kN) ? (i0 + f) : (kN - 1);
        const int jrow = 16 * jt + f;           // 0..63 (rows>=50 are zeros)

        f32x4 acc[4];
        #pragma unroll
        for (int k = 0; k < 4; ++k) acc[k] = (f32x4){0.f, 0.f, 0.f, 0.f};

        const float* __restrict__ aks[4] = {a0, a1, a2, a3};

        #pragma unroll
        for (int ksl = 0; ksl < 4; ++ksl) {
            const int dofs = 32 * ksl + 8 * g;

            // A-side: h_i f32 straight from Hf
            const float4 hA0 = *reinterpret_cast<const float4*>(&Hf[irow * HS32 + dofs]);
            const float4 hA1 = *reinterpret_cast<const float4*>(&Hf[irow * HS32 + dofs + 4]);
            const float ha[8] = {hA0.x, hA0.y, hA0.z, hA0.w, hA1.x, hA1.y, hA1.z, hA1.w};

            // B-side fragments (shared across k)
            const short8 bh = *reinterpret_cast<const short8*>(&Hhi[jrow * HS16 + dofs]);
            const short8 bl = *reinterpret_cast<const short8*>(&Hlo[jrow * HS16 + dofs]);

            #pragma unroll
            for (int k = 0; k < 4; ++k) {
                const float4 av0 = *reinterpret_cast<const float4*>(aks[k] + dofs);
                const float4 av1 = *reinterpret_cast<const float4*>(aks[k] + dofs + 4);
                const float aa[8] = {av0.x, av0.y, av0.z, av0.w, av1.x, av1.y, av1.z, av1.w};
                Pack8 ph, pl;
                #pragma unroll
                for (int p = 0; p < 4; ++p) {
                    const float q0 = ha[2 * p]     * aa[2 * p];
                    const float q1 = ha[2 * p + 1] * aa[2 * p + 1];
                    const uint32_t b0 = __float_as_uint(q0) & 0xffff0000u;
                    const uint32_t b1 = __float_as_uint(q1) & 0xffff0000u;
                    ph.u[p] = b1 | (b0 >> 16);
                    const float s0 = q0 - __uint_as_float(b0);
                    const float s1 = q1 - __uint_as_float(b1);
                    pl.u[p] = (__float_as_uint(s1) & 0xffff0000u) | (__float_as_uint(s0) >> 16);
                }
                acc[k] = __builtin_amdgcn_mfma_f32_16x16x32_bf16(ph.s, bh, acc[k], 0, 0, 0);
                acc[k] = __builtin_amdgcn_mfma_f32_16x16x32_bf16(ph.s, bl, acc[k], 0, 0, 0);
                acc[k] = __builtin_amdgcn_mfma_f32_16x16x32_bf16(pl.s, bh, acc[k], 0, 0, 0);
            }
        }

        // epilogue: select + leaky + mask via LDS adj -> final logits in Sa
        const int j = 16 * jt + f;
        #pragma unroll
        for (int reg = 0; reg < 4; ++reg) {
            const int iL = 16 * itL + 4 * g + reg;   // 0..31 local
            const int ii = 32 * ih + iL;             // global row
            if (ii < kN && j < kN) {
                const int kv = Ad[ii * ADS + j];
                const float val = (kv == 1) ? acc[0][reg]
                                : (kv == 2) ? acc[1][reg]
                                : (kv == 3) ? acc[2][reg]
                                : (kv == 4) ? acc[3][reg] : 0.f;
                const float lx = (val > 0.f) ? val : kSlope * val;
                Sa[iL * SS + j] = (kv >= 1 && kv <= 4) ? lx : kNeg;
            }
        }
    }
    __syncthreads();

    // ---------------- phase 3: softmax (wave per row) -> attn bf16 transposed ----------------
    {
        const int icount = ih ? (kN - 32) : 32;      // 18 or 32
        #pragma unroll
        for (int t = 0; t < 4; ++t) {
            const int rL = wid + 8 * t;              // 0..31
            if (rL < icount) {
                const float s = (lane < kN) ? Sa[rL * SS + lane] : kNeg;
                float m = s;
                #pragma unroll
                for (int o = 32; o; o >>= 1) m = fmaxf(m, __shfl_xor(m, o));
                const float e = (lane < kN) ? __expf(s - m) : 0.f;  // all-masked row -> uniform (matches ref)
                float ts = e;
                #pragma unroll
                for (int o = 32; o; o >>= 1) ts += __shfl_xor(ts, o);
                uint32_t u = __float_as_uint(e / ts);
                u += 0x7fffu + ((u >> 16) & 1u);     // round-to-nearest bf16
                At[lane * AS + rL] = (unsigned short)(u >> 16);
            }
        }
    }
    __syncthreads();

    // ---------------- phase 4: PV fp32: out[i,:] = sum_j attn[i,j] h[j,:] ----------------
    if (wid < 4) {
        const int itL = wid & 1;
        const int dh  = wid >> 1;
        const int i0L = 16 * itL;
        const int db  = 64 * dh + 4 * f;

        f32x4 o0 = {0.f, 0.f, 0.f, 0.f}, o1 = o0, o2 = o0, o3 = o0;
        #pragma unroll 5
        for (int j = 0; j < kN; ++j) {
            const float4  hv = *reinterpret_cast<const float4*>(&Hf[j * HS32 + db]);
            const ushort4 a4 = *reinterpret_cast<const ushort4*>(&At[j * AS + i0L + 4 * g]);
            const float av0 = __uint_as_float(((uint32_t)a4.x) << 16);
            const float av1 = __uint_as_float(((uint32_t)a4.y) << 16);
            const float av2 = __uint_as_float(((uint32_t)a4.z) << 16);
            const float av3 = __uint_as_float(((uint32_t)a4.w) << 16);
            o0.x += av0 * hv.x; o0.y += av0 * hv.y; o0.z += av0 * hv.z; o0.w += av0 * hv.w;
            o1.x += av1 * hv.x; o1.y += av1 * hv.y; o1.z += av1 * hv.z; o1.w += av1 * hv.w;
            o2.x += av2 * hv.x; o2.y += av2 * hv.y; o2.z += av2 * hv.z; o2.w += av2 * hv.w;
            o3.x += av3 * hv.x; o3.y += av3 * hv.y; o3.z += av3 * hv.z; o3.w += av3 * hv.w;
        }
        const int iiB = 32 * ih + i0L + 4 * g;
        if (iiB + 0 < kN) *reinterpret_cast<f32x4*>(&outb[(iiB + 0) * kD + db]) = o0;
        if (iiB + 1 < kN) *reinterpret_cast<f32x4*>(&outb[(iiB + 1) * kD + db]) = o1;
        if (iiB + 2 < kN) *reinterpret_cast<f32x4*>(&outb[(iiB + 2) * kD + db]) = o2;
        if (iiB + 3 < kN) *reinterpret_cast<f32x4*>(&outb[(iiB + 3) * kD + db]) = o3;
    }
}

extern "C" void kernel_launch(void* const* d_in, const int* in_sizes, int n_in,
                              void* d_out, int out_size, void* d_ws, size_t ws_size,
                              hipStream_t stream) {
    const float* hidden = reinterpret_cast<const float*>(d_in[0]);
    const int*   adjp   = reinterpret_cast<const int*>(d_in[1]);
    const float* a0     = reinterpret_cast<const float*>(d_in[2]);
    const float* a1     = reinterpret_cast<const float*>(d_in[3]);
    const float* a2     = reinterpret_cast<const float*>(d_in[4]);
    const float* a3     = reinterpret_cast<const float*>(d_in[5]);
    float*       outp   = reinterpret_cast<float*>(d_out);

    gat_v7_kernel<<<dim3(512), dim3(512), 0, stream>>>(
        hidden, adjp, a0, a1, a2, a3, outp);
}